// Round 1
// 1061.754 us; speedup vs baseline: 1.0685x; 1.0685x over previous
//
#include <hip/hip_runtime.h>
#include <hip/hip_bf16.h>

#define VOCAB 32000
#define HID   256
#define BATCH 32
#define SEQ   128
#define MROWS (BATCH * SEQ)  // 4096
#define NCB   250            // VOCAB / 128 column blocks

typedef _Float16 f16;
typedef _Float16 f16x4 __attribute__((ext_vector_type(4)));
typedef _Float16 f16x8 __attribute__((ext_vector_type(8)));
typedef float    f32x4 __attribute__((ext_vector_type(4)));

#define GLOAD_LDS16(gptr, lptr)                                                       \
  __builtin_amdgcn_global_load_lds(                                                   \
      (const __attribute__((address_space(1))) unsigned int*)(gptr),                  \
      (__attribute__((address_space(3))) unsigned int*)(lptr), 16, 0, 0)

// ---------------------------------------------------------------------------
// 1) embedding lookup + mask:  x[b,t,:] = (t < len[b]) ? emb[tok] : 0
// ---------------------------------------------------------------------------
__global__ __launch_bounds__(256) void embed_kernel(
    const int* __restrict__ tokens, const int* __restrict__ lengths,
    const float* __restrict__ emb, float* __restrict__ x) {
  int row = blockIdx.x;            // b*SEQ + t
  int b = row >> 7, t = row & 127;
  int tok = tokens[row];
  float v = (t < lengths[b]) ? emb[(size_t)tok * HID + threadIdx.x] : 0.f;
  x[(size_t)row * HID + threadIdx.x] = v;
}

// ---------------------------------------------------------------------------
// 2) fp32 -> fp16 cast (float4 -> 4 halfs per thread)
// ---------------------------------------------------------------------------
__global__ __launch_bounds__(256) void cast_kernel(
    const float* __restrict__ in, f16* __restrict__ out, int n4) {
  int idx = blockIdx.x * 256 + threadIdx.x;
  if (idx >= n4) return;
  float4 v = ((const float4*)in)[idx];
  f16x4 o = {(f16)v.x, (f16)v.y, (f16)v.z, (f16)v.w};
  ((f16x4*)out)[idx] = o;
}

// ---------------------------------------------------------------------------
// 3) X = In @ W^T + bias   (In: [4096][256], W: [256][256] row-major, fp32)
// ---------------------------------------------------------------------------
__global__ __launch_bounds__(256) void xprep_kernel(
    const float* __restrict__ In, const float* __restrict__ W,
    const float* __restrict__ bias, float* __restrict__ Out) {
  __shared__ float sIn[16 * 256];
  int tid = threadIdx.x;
  int rb = blockIdx.x * 16;
  const float4* g = (const float4*)(In + (size_t)rb * 256);
  float4* s4 = (float4*)sIn;
#pragma unroll
  for (int q = 0; q < 4; ++q) s4[tid + q * 256] = g[tid + q * 256];
  __syncthreads();
  int i = tid;
  float acc[16];
#pragma unroll
  for (int r = 0; r < 16; ++r) acc[r] = 0.f;
  const float4* w4 = (const float4*)(W + (size_t)i * 256);
#pragma unroll 4
  for (int j = 0; j < 64; ++j) {
    float4 wv = w4[j];
#pragma unroll
    for (int r = 0; r < 16; ++r) {
      float4 sv = ((const float4*)(sIn + r * 256))[j];
      acc[r] += sv.x * wv.x + sv.y * wv.y + sv.z * wv.z + sv.w * wv.w;
    }
  }
  float bi = bias[i];
#pragma unroll
  for (int r = 0; r < 16; ++r) Out[(size_t)(rb + r) * 256 + i] = acc[r] + bi;
}

// ---------------------------------------------------------------------------
// 4) recurrence: h_t = tanh(X_t + h_{t-1} @ Wh^T); output masked, carry unmasked
// ---------------------------------------------------------------------------
__global__ __launch_bounds__(512) void rnn_kernel(
    const float* __restrict__ X, const float* __restrict__ Wh,
    const int* __restrict__ lengths, float* __restrict__ Hout) {
  int b = blockIdx.x;
  int tid = threadIdx.x;
  int i = tid & 255;
  int half = tid >> 8;  // wave-uniform
  float w[128];
  {
    const float4* wr = (const float4*)(Wh + (size_t)i * 256 + half * 128);
#pragma unroll
    for (int q = 0; q < 32; ++q) {
      float4 v = wr[q];
      w[4 * q + 0] = v.x; w[4 * q + 1] = v.y;
      w[4 * q + 2] = v.z; w[4 * q + 3] = v.w;
    }
  }
  __shared__ float sh[256];
  __shared__ float sp[256];
  if (tid < 256) sh[tid] = 0.f;
  int len = lengths[b];
  const float* Xb = X + (size_t)b * SEQ * HID;
  float* Hb = Hout + (size_t)b * SEQ * HID;
  __syncthreads();
  float xnext = (half == 0) ? Xb[i] : 0.f;
  for (int t = 0; t < SEQ; ++t) {
    float a0 = 0.f, a1 = 0.f, a2 = 0.f, a3 = 0.f;
    const float4* hp = (const float4*)(sh + half * 128);
#pragma unroll
    for (int q = 0; q < 32; ++q) {
      float4 hv = hp[q];
      a0 += hv.x * w[4 * q + 0];
      a1 += hv.y * w[4 * q + 1];
      a2 += hv.z * w[4 * q + 2];
      a3 += hv.w * w[4 * q + 3];
    }
    float acc = (a0 + a1) + (a2 + a3);
    if (half) sp[i] = acc;
    __syncthreads();
    if (!half) {
      float h = tanhf(xnext + acc + sp[i]);
      Hb[(size_t)t * HID + i] = (t < len) ? h : 0.f;  // masked output
      sh[i] = h;                                      // unmasked carry
      if (t + 1 < SEQ) xnext = Xb[(size_t)(t + 1) * HID + i];
    }
    __syncthreads();
  }
}

// ---------------------------------------------------------------------------
// 5) Two-pass fused GEMM+softmax.
//    Pass 1 (WRITE_PROBS=0): logits in registers only -> per-block online
//      softmax partials (row max, sum exp) to PM/PL. NO 524MB logits write.
//    Pass 2 (WRITE_PROBS=1): recompute identical MFMA accumulators, apply
//      probs = exp(acc - Mrow)*Inv (0 for padded rows), write probs directly.
//    Saves 2x 524MB of HBM traffic vs. write-logits + normalize-RMW.
// ---------------------------------------------------------------------------
template <int WRITE_PROBS>
__global__ __launch_bounds__(256) void gemm_kernel(
    const f16* __restrict__ A,   // [4096][256] masked h2
    const f16* __restrict__ Bm,  // [32000][256] emb
    float* __restrict__ C,       // [4096][32000] probs (pass 2 only)
    float* __restrict__ PM,      // [4096][250] partial row max (pass 1)
    float* __restrict__ PL,      // [4096][250] partial sum exp (pass 1)
    const float* __restrict__ Mrow,  // [4096] row max (pass 2)
    const float* __restrict__ Inv,   // [4096] 1/denominator (pass 2)
    const int* __restrict__ lengths) {
  __shared__ __align__(16) f16 sA[128 * 64];
  __shared__ __align__(16) f16 sB[128 * 64];
  __shared__ float sM[128];
  __shared__ float sI[128];
  const int tid = threadIdx.x;
  const int wave = tid >> 6;
  const int lane = tid & 63;
  const int row0 = blockIdx.x * 128;  // 32 blocks; row tile == batch blockIdx.x
  const int col0 = blockIdx.y * 128;  // 250 blocks

  if (WRITE_PROBS) {
    if (tid < 128) {
      sM[tid] = Mrow[row0 + tid];
      sI[tid] = Inv[row0 + tid];
    }
  }

  f32x4 acc[4][4];
#pragma unroll
  for (int a = 0; a < 4; ++a)
#pragma unroll
    for (int b = 0; b < 4; ++b) acc[a][b] = (f32x4){0.f, 0.f, 0.f, 0.f};

  const int lr = lane >> 3;  // row within 8-row group
  const int ls = lane & 7;   // LDS 16B slot within row
  const int wm = wave & 1, wn = wave >> 1;

  for (int ko = 0; ko < 4; ++ko) {
#pragma unroll
    for (int ii = 0; ii < 4; ++ii) {
      int ar = wave * 32 + ii * 8;  // tile-row base (wave-uniform)
      int r = ar + lr;
      int c = ls ^ (r & 7);         // swizzled 16B-chunk index
      const f16* ga = A + (size_t)(row0 + r) * 256 + ko * 64 + c * 8;
      GLOAD_LDS16(ga, sA + ar * 64);
      const f16* gb = Bm + (size_t)(col0 + r) * 256 + ko * 64 + c * 8;
      GLOAD_LDS16(gb, sB + ar * 64);
    }
    __syncthreads();
#pragma unroll
    for (int kk = 0; kk < 2; ++kk) {
      f16x8 af[4], bf[4];
#pragma unroll
      for (int f = 0; f < 4; ++f) {
        int m = wm * 64 + f * 16 + (lane & 15);
        int cA = kk * 4 + (lane >> 4);
        af[f] = *(const f16x8*)(sA + m * 64 + (cA ^ (m & 7)) * 8);
        int n = wn * 64 + f * 16 + (lane & 15);
        bf[f] = *(const f16x8*)(sB + n * 64 + (cA ^ (n & 7)) * 8);
      }
#pragma unroll
      for (int fm = 0; fm < 4; ++fm)
#pragma unroll
        for (int fn = 0; fn < 4; ++fn)
          acc[fm][fn] = __builtin_amdgcn_mfma_f32_16x16x32_f16(
              af[fm], bf[fn], acc[fm][fn], 0, 0, 0);
    }
    __syncthreads();
  }

  const int lq = lane >> 4;
  const int lc = lane & 15;

  if (WRITE_PROBS) {
    // --- pass 2: probs = exp(acc - m) * inv, masked rows -> 0 ---
    // C/D layout: col=lane&15, row=(lane>>4)*4+reg
    int len = lengths[blockIdx.x];  // row tile == one batch element
#pragma unroll
    for (int fm = 0; fm < 4; ++fm)
#pragma unroll
      for (int fn = 0; fn < 4; ++fn)
#pragma unroll
        for (int rr = 0; rr < 4; ++rr) {
          int t = wm * 64 + fm * 16 + lq * 4 + rr;  // t within batch
          int col = col0 + wn * 64 + fn * 16 + lc;
          float v =
              (t < len) ? __expf(acc[fm][fn][rr] - sM[t]) * sI[t] : 0.f;
          C[(size_t)(row0 + t) * VOCAB + col] = v;
        }
  } else {
    // --- pass 1: per-block online-softmax partials; reuse sA as scratch ---
    // (last __syncthreads in k-loop already executed; all waves past MFMA)
    float* rm = (float*)sA;        // [2][128]  per-wn per-row max
    float* rs = rm + 256;          // [2][128]  per-wn per-row sum exp
#pragma unroll
    for (int fm = 0; fm < 4; ++fm)
#pragma unroll
      for (int rr = 0; rr < 4; ++rr) {
        float mx = fmaxf(fmaxf(acc[fm][0][rr], acc[fm][1][rr]),
                         fmaxf(acc[fm][2][rr], acc[fm][3][rr]));
#pragma unroll
        for (int off = 1; off < 16; off <<= 1)
          mx = fmaxf(mx, __shfl_xor(mx, off, 64));
        float sum = __expf(acc[fm][0][rr] - mx) + __expf(acc[fm][1][rr] - mx) +
                    __expf(acc[fm][2][rr] - mx) + __expf(acc[fm][3][rr] - mx);
#pragma unroll
        for (int off = 1; off < 16; off <<= 1) sum += __shfl_xor(sum, off, 64);
        if (lc == 0) {
          int r = wm * 64 + fm * 16 + lq * 4 + rr;
          rm[wn * 128 + r] = mx;
          rs[wn * 128 + r] = sum;
        }
      }
    __syncthreads();
    if (tid < 128) {
      float m0 = rm[tid], m1 = rm[128 + tid];
      float M = fmaxf(m0, m1);
      float L = rs[tid] * __expf(m0 - M) + rs[128 + tid] * __expf(m1 - M);
      PM[(size_t)(row0 + tid) * NCB + blockIdx.y] = M;
      PL[(size_t)(row0 + tid) * NCB + blockIdx.y] = L;
    }
  }
}

// ---------------------------------------------------------------------------
// 6) combine 250 partials per row -> m[row], inv[row]. One wave per row.
// ---------------------------------------------------------------------------
__global__ __launch_bounds__(256) void combine_kernel(
    const float* __restrict__ PM, const float* __restrict__ PL,
    float* __restrict__ Mrow, float* __restrict__ Inv) {
  int row = blockIdx.x * 4 + (threadIdx.x >> 6);
  int lane = threadIdx.x & 63;
  const float* pm = PM + (size_t)row * NCB;
  const float* pl = PL + (size_t)row * NCB;
  float M = -3.4e38f;
  for (int i = lane; i < NCB; i += 64) M = fmaxf(M, pm[i]);
#pragma unroll
  for (int off = 1; off < 64; off <<= 1) M = fmaxf(M, __shfl_xor(M, off, 64));
  float L = 0.f;
  for (int i = lane; i < NCB; i += 64) L += pl[i] * __expf(pm[i] - M);
#pragma unroll
  for (int off = 1; off < 64; off <<= 1) L += __shfl_xor(L, off, 64);
  if (lane == 0) {
    Mrow[row] = M;
    Inv[row] = 1.f / L;
  }
}

// ---------------------------------------------------------------------------
extern "C" void kernel_launch(void* const* d_in, const int* in_sizes, int n_in,
                              void* d_out, int out_size, void* d_ws,
                              size_t ws_size, hipStream_t stream) {
  const int* tokens = (const int*)d_in[0];
  const int* lengths = (const int*)d_in[1];
  const float* emb = (const float*)d_in[2];
  const float* Wx1 = (const float*)d_in[3];
  const float* Wh1 = (const float*)d_in[4];
  const float* b1 = (const float*)d_in[5];
  const float* Wx2 = (const float*)d_in[6];
  const float* Wh2 = (const float*)d_in[7];
  const float* b2 = (const float*)d_in[8];

  float* probs = (float*)d_out;
  float* h2out = probs + (size_t)MROWS * VOCAB;  // [4096][256] masked h2

  float* ws = (float*)d_ws;
  float* x = ws;                               // 1,048,576 f
  float* X = ws + 1048576;                     // 1,048,576 f (reused layer 2)
  float* h1 = ws + 2097152;                    // 1,048,576 f
  f16* embh = (f16*)(ws + 3145728);            // 8,192,000 halfs = 4,096,000 f
  f16* h2h = (f16*)(ws + 3145728 + 4096000);   // 1,048,576 halfs = 524,288 f
  float* PM = ws + 7766016;                    // 1,024,000 f
  float* PL = ws + 8790016;                    // 1,024,000 f
  float* Mrow = ws + 9814016;                  // 4096 f
  float* Inv = ws + 9818112;                   // 4096 f

  embed_kernel<<<MROWS, 256, 0, stream>>>(tokens, lengths, emb, x);
  cast_kernel<<<8000, 256, 0, stream>>>(emb, embh, VOCAB * HID / 4);

  xprep_kernel<<<256, 256, 0, stream>>>(x, Wx1, b1, X);
  rnn_kernel<<<BATCH, 512, 0, stream>>>(X, Wh1, lengths, h1);
  xprep_kernel<<<256, 256, 0, stream>>>(h1, Wx2, b2, X);
  rnn_kernel<<<BATCH, 512, 0, stream>>>(X, Wh2, lengths, h2out);

  cast_kernel<<<1024, 256, 0, stream>>>(h2out, h2h, MROWS * HID / 4);

  dim3 gg(32, NCB);
  // pass 1: partials only (no 524MB logits write)
  gemm_kernel<0><<<gg, 256, 0, stream>>>(h2h, embh, nullptr, PM, PL,
                                         nullptr, nullptr, nullptr);
  combine_kernel<<<MROWS / 4, 256, 0, stream>>>(PM, PL, Mrow, Inv);
  // pass 2: recompute + fused exp/scale/mask, write probs directly
  gemm_kernel<1><<<gg, 256, 0, stream>>>(h2h, embh, probs, nullptr, nullptr,
                                         Mrow, Inv, lengths);
}